// Round 8
// baseline (377.686 us; speedup 1.0000x reference)
//
#include <hip/hip_runtime.h>

// KerasCustomMappingLayer: B=32768 rows x H=512 sequential steps, out (B,H,6) f32.
//
// R8: WAVE-PER-ROW, SEGMENT-PARALLEL. R1-R7 established: thread-per-row chunking
// is pinned at ~3.6 TB/s (every wave op touches 64 distinct 8KB-strided lines)
// with >=950MB traffic (replay+boundary refetch) -> floor ~264us = R6's 270us.
// New structure: one wave per row.
//   load : row's 8KB coalesced -> LDS (dense stream, 1KB/instr)
//   comp : reset-delimited segments (l[k]>192, k-only => same boundaries for all
//          rows; ~129 segs/row, avg len ~4) distributed over 64 lanes; each lane
//          runs its segments serially from LDS, outputs -> 12KB LDS staging
//   store: output row coalesced from LDS (dense stream)
// Zero replay => bytes = true minimum (~671MB). Dense streams => copy-kernel BW
// ceiling (~6.3TB/s), not the 3.6 scatter ceiling.
// Numerics: exact numpy fp32 graph for everything feeding the (px,py) carry
// (contract off, IEEE div/sqrt -> wall comparisons never flip). Output-only
// /512 -> exact pow2 multiply (bit-identical); /384 -> multiply (<=1ulp, pure
// output, never compared).
// Frozen lessons: plain stores only (R2 NT = 2.6x WRITE); full-line vector
// access on both sides (R1); no ragged scalar global stores (R4).

#define H 512
#define RPB 2   // rows per block (2 waves x 64)

__device__ __forceinline__ void step_core(
    float m0, float m1, float m2, float m3,
    float lk, float isslf, float slnk, float scosk, float ssink,
    bool nfse, float& px, float& py, float* __restrict__ o)
{
#pragma clang fp contract(off)
    const float WL = (float)(0.05 * 512.0);
    const float WR = (float)(0.95 * 512.0);
    const float WT = (float)(0.05 * 384.0);
    const float WB = (float)(0.95 * 384.0);

    float q0 = __fmul_rn(m0, m0);
    float q2 = __fmul_rn(m2, m2);
    float len1 = __fsqrt_rn(__fadd_rn(q0, q2));
    float ck = __fdiv_rn(m0, len1);
    float sk = __fdiv_rn(m2, len1);
    float q1 = __fmul_rn(m1, m1);
    float q3 = __fmul_rn(m3, m3);
    float len2 = __fsqrt_rn(__fadd_rn(q1, q3));
    float ck2 = __fdiv_rn(m1, len2);
    float sk2 = __fdiv_rn(m3, len2);

    bool rr = lk > 192.0f;                 // l > Y_MAX/2  (the carry reset)
    float half_l = __fmul_rn(lk, 0.5f);
    float wl = __fadd_rn(WL, half_l);
    float wr = __fadd_rn(WR, -half_l);
    float wt = __fadd_rn(WT, half_l);
    float wb = __fadd_rn(WB, -half_l);

    float dx = __fmul_rn(lk, ck);
    float dy = __fmul_rn(lk, sk);
    float adx = fabsf(dx);
    float ady = fabsf(dy);

    float xd = (px < wl) ? adx : ((px > wr) ? -adx : (((px > wl) && (px < wr)) ? dx : 0.0f));
    float yd = (py < wt) ? ady : ((py > wb) ? -ady : (((py > wt) && (py < wb)) ? dy : 0.0f));

    float rx = __fadd_rn(256.0f, __fmul_rn(256.0f, m0));
    float ry = __fadd_rn(192.0f, __fmul_rn(192.0f, m2));

    float _x = rr ? rx : __fadd_rn(px, xd);
    float _y = rr ? ry : __fadd_rn(py, yd);

    bool issl = isslf != 0.0f;
    float e1 = __fmul_rn(ck2, slnk);
    float e2 = __fmul_rn(sk2, slnk);
    float ex = __fadd_rn(_x, e1);
    float ey = __fadd_rn(_y, e2);

    // outputs: /512 as exact pow2 mul (bit-identical to div); /384 as mul
    // (<=1ulp vs div; outputs never feed comparisons/carry)
    float o0 = __fmul_rn(_x, 1.0f / 512.0f);
    float o1 = __fmul_rn(_y, 1.0f / 384.0f);
    o[0] = o0;
    o[1] = o1;
    if (issl) {
        float t1 = __fmul_rn(ck2, scosk);
        float t2 = __fmul_rn(sk2, ssink);
        o[2] = __fadd_rn(t1, -t2);
        float t3 = __fmul_rn(ck2, ssink);
        float t4 = __fmul_rn(sk2, scosk);
        o[3] = __fadd_rn(t3, t4);
        o[4] = __fmul_rn(ex, 1.0f / 512.0f);
        o[5] = __fmul_rn(ey, 1.0f / 384.0f);
        px = nfse ? ex : _x;
        py = nfse ? ey : _y;
    } else {
        o[2] = rr ? ck2 : ck;
        o[3] = rr ? sk2 : sk;
        o[4] = o0;
        o[5] = o1;
        px = _x;
        py = _y;
    }
}

__global__ __launch_bounds__(RPB * 64)
void construct_map_wave(const float* __restrict__ mapvars,
                        const float* __restrict__ rel,
                        const float* __restrict__ start_pos,
                        const float* __restrict__ lmul,
                        const int* __restrict__ nfse_p,
                        float* __restrict__ out)
{
    __shared__ float s_issl[H];
    __shared__ float s_slen[H];
    __shared__ float s_scos[H];
    __shared__ float s_ssin[H];
    __shared__ float s_lk[H];
    __shared__ int   seg_list[H + 1];
    __shared__ int   nseg_s;
    __shared__ float4 lds_in[RPB][H];            // 16KB: 2 rows x 2048 floats
    __shared__ float4 lds_out[RPB][H * 6 / 4];   // 24KB: 2 rows x 3072 floats

    const int tid = threadIdx.x;
    const int w = tid >> 6;
    const int lane = tid & 63;
    const int row = blockIdx.x * RPB + w;

    // stage rel-derived per-step constants (block-shared)
    float lm = lmul[0];
    for (int i = tid; i < H; i += RPB * 64) {
        s_issl[i] = rel[i];
        s_slen[i] = rel[H + i];
        s_scos[i] = rel[3 * H + i];
        s_ssin[i] = rel[4 * H + i];
        s_lk[i]   = __fmul_rn(lm, rel[5 * H + i]);
    }

    // stage this wave's input row: 8KB coalesced (8 x 1KB wave bursts)
    const float4* rp4 = (const float4*)(mapvars + (size_t)row * (4 * H));
#pragma unroll
    for (int i = 0; i < 8; ++i)
        lds_in[w][i * 64 + lane] = rp4[i * 64 + lane];

    __syncthreads();

    // wave 0 builds the segment list (k-only, shared by all rows):
    // starts = {0} U {k : l[k] > 192}; ballot+popcount prefix placement
    if (tid < 64) {
        int base = 0;
        for (int c = 0; c < H / 64; ++c) {
            int k = c * 64 + tid;
            bool isr = (k == 0) || (s_lk[k] > 192.0f);
            unsigned long long m = __ballot(isr);
            int idx = base + __popcll(m & ((1ull << tid) - 1ull));
            if (isr) seg_list[idx] = k;
            base += __popcll(m);
        }
        if (tid == 0) { seg_list[base] = H; nseg_s = base; }
    }
    __syncthreads();

    const int nseg = nseg_s;
    const bool nfse = (nfse_p[0] != 0);
    const float sx = start_pos[0], sy = start_pos[1];
    const float* __restrict__ inf  = (const float*)&lds_in[w][0];
    float* __restrict__ outf = (float*)&lds_out[w][0];

    // segments are independent (carry dead at every reset); lanes take
    // segments round-robin. Divergence = per-round max segment length.
    for (int sid = lane; sid < nseg; sid += 64) {
        const int k0 = seg_list[sid];
        const int k1 = seg_list[sid + 1];
        float px = 0.0f, py = 0.0f;
        if (k0 == 0) { px = sx; py = sy; }
        for (int k = k0; k < k1; ++k) {
            step_core(inf[k], inf[H + k], inf[2 * H + k], inf[3 * H + k],
                      s_lk[k], s_issl[k], s_slen[k], s_scos[k], s_ssin[k],
                      nfse, px, py, outf + 6 * k);
        }
    }

    __syncthreads();   // cross-lane LDS visibility before coalesced store

    // store this wave's output row: 12KB coalesced (12 x 1KB wave bursts)
    float4* ow4 = (float4*)(out + (size_t)row * (H * 6));
    const float4* lo4 = (const float4*)&lds_out[w][0];
#pragma unroll
    for (int i = 0; i < 12; ++i)
        ow4[i * 64 + lane] = lo4[i * 64 + lane];
}

extern "C" void kernel_launch(void* const* d_in, const int* in_sizes, int n_in,
                              void* d_out, int out_size, void* d_ws, size_t ws_size,
                              hipStream_t stream) {
    const float* mapvars = (const float*)d_in[0];
    const float* rel     = (const float*)d_in[1];
    const float* sp      = (const float*)d_in[2];
    const float* lm      = (const float*)d_in[3];
    const int*   nfse    = (const int*)d_in[4];
    float* out = (float*)d_out;

    const int B = in_sizes[0] / (4 * H);   // 32768
    hipLaunchKernelGGL(construct_map_wave, dim3(B / RPB), dim3(RPB * 64), 0, stream,
                       mapvars, rel, sp, lm, nfse, out);
}

// Round 9
// 193.495 us; speedup vs baseline: 1.9519x; 1.9519x over previous
//
#include <hip/hip_runtime.h>

// KerasCustomMappingLayer: B=32768 rows x H=512 sequential steps, out (B,H,6) f32.
//
// R9: wave-per-row (R8's proven minimal-traffic structure: FETCH 131MB,
// WRITE 393MB) with the compute restructured into A/B/C phases:
//   A (k-parallel, dense): sqrt/div-heavy per-k math -> LDS + regs. 0 divergence.
//   B (divergent, CHEAP):  px/py carry chain = walls+adds+selects only
//                          (~20 instr/step vs ~240 in R8's fused step).
//   C (k-parallel, dense): output assembly + dense stores.
// Half-row staging (256 steps) cuts LDS to 8KB/row; 4 rows/block -> 39KB ->
// 4 blocks/CU = 16 waves/CU (R8: 5.5). k = lane+64j strips make every per-k
// LDS array access bank-conflict-free (bank = lane%32) AND every global
// access dense (256B/burst loads, 1.5KB-contiguous store bursts).
// Segments (carry resets at l[k]>192, k-only) assigned lane=sid%64; carries
// crossing the half boundary persist in per-slot registers (static unroll).
// Numerics: carry path bit-identical to numpy fp32 (contract off, IEEE
// div/sqrt, per-step rr = lk>192); outputs use pow2-exact *1/512 and *1/384
// mul (proven R8: absmax unchanged).
// Frozen lessons: plain stores (R2), no ragged scalar global stores (R4),
// no VGPR squeeze below need (R5).

#define H 512
#define RPB 4      // rows per block = waves per block
#define HALF 256   // k-steps staged per phase

typedef float v2f __attribute__((ext_vector_type(2)));

__global__ __launch_bounds__(256, 4)
void construct_map_seg(const float* __restrict__ mapvars,
                       const float* __restrict__ rel,
                       const float* __restrict__ start_pos,
                       const float* __restrict__ lmul,
                       const int* __restrict__ nfse_p,
                       float* __restrict__ out)
{
#pragma clang fp contract(off)
    __shared__ float s_lk[H];
    __shared__ float s_issl[H];
    __shared__ int   seg_list[H + 8];
    __shared__ int   nseg_s;
    __shared__ float bd_dx[RPB][HALF];
    __shared__ float bd_dy[RPB][HALF];
    __shared__ float bd_e1[RPB][HALF];
    __shared__ float bd_e2[RPB][HALF];
    __shared__ float bd_rx[RPB][HALF];
    __shared__ float bd_ry[RPB][HALF];
    __shared__ float bd_xx[RPB][HALF];
    __shared__ float bd_yy[RPB][HALF];

    const int tid = threadIdx.x;
    const int w = tid >> 6;
    const int lane = tid & 63;
    const int row = blockIdx.x * RPB + w;

    const float lm = lmul[0];
    for (int i = tid; i < H; i += 256) {
        s_lk[i] = __fmul_rn(lm, rel[5 * H + i]);   // l = lmul * note_dist
        s_issl[i] = rel[i];                        // is_slider
    }
    __syncthreads();

    // segment list: starts = {0} U {k : l[k] > 192}  (k-only, all rows share)
    if (tid < 64) {
        int base = 0;
        for (int c = 0; c < H / 64; ++c) {
            int k = c * 64 + tid;
            bool isr = (k == 0) || (s_lk[k] > 192.0f);
            unsigned long long m = __ballot(isr);
            int idx = base + __popcll(m & ((1ull << tid) - 1ull));
            if (isr) seg_list[idx] = k;
            base += __popcll(m);
        }
        if (tid == 0) { seg_list[base] = H; nseg_s = base; }
    }
    __syncthreads();

    const int nseg = nseg_s;
    const bool nfse = (nfse_p[0] != 0);
    const float sx = start_pos[0], sy = start_pos[1];

    const float WL = (float)(0.05 * 512.0);
    const float WR = (float)(0.95 * 512.0);
    const float WT = (float)(0.05 * 384.0);
    const float WB = (float)(0.95 * 384.0);

    const float* rowp = mapvars + (size_t)row * (4 * H);
    float* orow = out + (size_t)row * (H * 6);

    float pxs0 = 0.f, pys0 = 0.f, pxs1 = 0.f, pys1 = 0.f;
    float pxs2 = 0.f, pys2 = 0.f, pxs3 = 0.f, pys3 = 0.f;

    for (int h = 0; h < 2; ++h) {
        const int kb = h * HALF;
        float o2r[4], o3r[4], e1r[4], e2r[4];

        // ---- A: heavy per-k math, dense, all lanes active ----
#pragma unroll
        for (int j = 0; j < 4; ++j) {
            const int kk = lane + 64 * j;
            const int k = kb + kk;
            float m0 = rowp[k];
            float m1 = rowp[H + k];
            float m2 = rowp[2 * H + k];
            float m3 = rowp[3 * H + k];
            float sln  = rel[H + k];
            float scos = rel[3 * H + k];
            float ssin = rel[4 * H + k];
            float lk  = s_lk[k];
            float isf = s_issl[k];

            float len1 = __fsqrt_rn(__fadd_rn(__fmul_rn(m0, m0), __fmul_rn(m2, m2)));
            float ck = __fdiv_rn(m0, len1);
            float sk = __fdiv_rn(m2, len1);
            float len2 = __fsqrt_rn(__fadd_rn(__fmul_rn(m1, m1), __fmul_rn(m3, m3)));
            float ck2 = __fdiv_rn(m1, len2);
            float sk2 = __fdiv_rn(m3, len2);

            float dx = __fmul_rn(lk, ck);
            float dy = __fmul_rn(lk, sk);
            float rx = __fadd_rn(256.0f, __fmul_rn(256.0f, m0));
            float ry = __fadd_rn(192.0f, __fmul_rn(192.0f, m2));
            float e1 = __fmul_rn(ck2, sln);
            float e2 = __fmul_rn(sk2, sln);
            bool rr  = lk > 192.0f;
            bool isl = isf != 0.0f;
            float oa = __fadd_rn(__fmul_rn(ck2, scos), -__fmul_rn(sk2, ssin));
            float ob = __fadd_rn(__fmul_rn(ck2, ssin),  __fmul_rn(sk2, scos));
            o2r[j] = isl ? oa : (rr ? ck2 : ck);
            o3r[j] = isl ? ob : (rr ? sk2 : sk);
            e1r[j] = e1; e2r[j] = e2;
            bd_dx[w][kk] = dx; bd_dy[w][kk] = dy;
            bd_e1[w][kk] = e1; bd_e2[w][kk] = e2;
            bd_rx[w][kk] = rx; bd_ry[w][kk] = ry;
        }
        __syncthreads();

        // ---- B: serial carry chain, cheap steps, segment-parallel ----
#pragma unroll
        for (int slot = 0; slot < 4; ++slot) {
            const int sid = lane + 64 * slot;
            if (sid < nseg) {
                const int k0 = seg_list[sid];
                const int k1 = seg_list[sid + 1];
                const int lo = (k0 > kb) ? k0 : kb;
                const int hi = (k1 < kb + HALF) ? k1 : (kb + HALF);
                float px, py;
                if (k0 >= kb) {              // segment starts in this half
                    px = (k0 == 0) ? sx : 0.0f;
                    py = (k0 == 0) ? sy : 0.0f;
                } else {                     // continues from previous half
                    px = (slot == 0) ? pxs0 : (slot == 1) ? pxs1 : (slot == 2) ? pxs2 : pxs3;
                    py = (slot == 0) ? pys0 : (slot == 1) ? pys1 : (slot == 2) ? pys2 : pys3;
                }
                for (int k = lo; k < hi; ++k) {
                    const int kk = k - kb;
                    float lk = s_lk[k];
                    float _x, _y;
                    if (lk > 192.0f) {       // rerand: carry-independent
                        _x = bd_rx[w][kk];
                        _y = bd_ry[w][kk];
                    } else {
                        float hl = __fmul_rn(lk, 0.5f);
                        float wl = __fadd_rn(WL, hl);
                        float wr = __fadd_rn(WR, -hl);
                        float wt = __fadd_rn(WT, hl);
                        float wb = __fadd_rn(WB, -hl);
                        float dx = bd_dx[w][kk], dy = bd_dy[w][kk];
                        float adx = fabsf(dx), ady = fabsf(dy);
                        float xd = (px < wl) ? adx : ((px > wr) ? -adx : (((px > wl) && (px < wr)) ? dx : 0.0f));
                        float yd = (py < wt) ? ady : ((py > wb) ? -ady : (((py > wt) && (py < wb)) ? dy : 0.0f));
                        _x = __fadd_rn(px, xd);
                        _y = __fadd_rn(py, yd);
                    }
                    bd_xx[w][kk] = _x;
                    bd_yy[w][kk] = _y;
                    if ((s_issl[k] != 0.0f) && nfse) {
                        px = __fadd_rn(_x, bd_e1[w][kk]);
                        py = __fadd_rn(_y, bd_e2[w][kk]);
                    } else { px = _x; py = _y; }
                }
                if (slot == 0) { pxs0 = px; pys0 = py; }
                else if (slot == 1) { pxs1 = px; pys1 = py; }
                else if (slot == 2) { pxs2 = px; pys2 = py; }
                else { pxs3 = px; pys3 = py; }
            }
        }
        __syncthreads();

        // ---- C: output assembly, dense stores (1.5KB-contiguous bursts) ----
#pragma unroll
        for (int j = 0; j < 4; ++j) {
            const int kk = lane + 64 * j;
            const int k = kb + kk;
            float _x = bd_xx[w][kk], _y = bd_yy[w][kk];
            float o0 = __fmul_rn(_x, 1.0f / 512.0f);
            float o1 = __fmul_rn(_y, 1.0f / 384.0f);
            bool isl = s_issl[k] != 0.0f;
            float o4 = o0, o5 = o1;
            if (isl) {
                o4 = __fmul_rn(__fadd_rn(_x, e1r[j]), 1.0f / 512.0f);
                o5 = __fmul_rn(__fadd_rn(_y, e2r[j]), 1.0f / 384.0f);
            }
            float* op = orow + (size_t)k * 6;
            v2f a = {o0, o1};
            v2f b = {o2r[j], o3r[j]};
            v2f c = {o4, o5};
            *(v2f*)(op)     = a;
            *(v2f*)(op + 2) = b;
            *(v2f*)(op + 4) = c;
        }
        __syncthreads();
    }
}

extern "C" void kernel_launch(void* const* d_in, const int* in_sizes, int n_in,
                              void* d_out, int out_size, void* d_ws, size_t ws_size,
                              hipStream_t stream) {
    const float* mapvars = (const float*)d_in[0];
    const float* rel     = (const float*)d_in[1];
    const float* sp      = (const float*)d_in[2];
    const float* lm      = (const float*)d_in[3];
    const int*   nfse    = (const int*)d_in[4];
    float* out = (float*)d_out;

    const int B = in_sizes[0] / (4 * H);   // 32768
    hipLaunchKernelGGL(construct_map_seg, dim3(B / RPB), dim3(256), 0, stream,
                       mapvars, rel, sp, lm, nfse, out);
}